// Round 10
// baseline (204.422 us; speedup 1.0000x reference)
//
#include <hip/hip_runtime.h>

#define E 4096
#define H 32
#define L 8192
#define SCALE 0.08838834764831845f  // 1/sqrt(128)

// workspace layout (float offsets)
#define WS_QACC 0                 // 4 reps x 4096
#define WS_KACC 16384             // 4 reps x 4096
#define WS_VACC 32768             // 4 reps x 4096
#define WS_OACC 49152             // 4096
#define WS_NUMP 53248             // 16 reps x 4096
#define WS_DENP 118784            // 16 reps x 64
#define WS_NUM  119808            // 4096
#define WS_DEN  123904            // 64
#define WS_ZERO_FLOATS 123968

typedef float fv4 __attribute__((ext_vector_type(4)));

__device__ __forceinline__ fv4 ntload4(const float* p) {
  return __builtin_nontemporal_load(reinterpret_cast<const fv4*>(p));
}

// ---------------- K0: zero accumulator region -------------------------------
__global__ __launch_bounds__(256) void zero_ws(float* __restrict__ ws) {
  int i = blockIdx.x * 256 + threadIdx.x;
  if (i < WS_ZERO_FLOATS) ws[i] = 0.f;
}

// ---------------- K1: fused q/k/v GEMV (split-K, replicated partials) -------
__global__ __launch_bounds__(256) void gemv_qkv(const float* __restrict__ x,
    const float* __restrict__ Wq, const float* __restrict__ Wk,
    const float* __restrict__ Wv, float* __restrict__ ws) {
  int b = blockIdx.x;            // 384 blocks: 3 mats x 32 chunks x 4 col-groups
  int mat = b >> 7;
  int rem = b & 127;
  int chunk = rem >> 2;          // 32 chunks of 128 rows
  int g = rem & 3;               // 4 col groups of 1024
  const float* W = (mat == 0) ? Wq : (mat == 1) ? Wk : Wv;
  int rep = (b >> 2) & 3;        // varies across blocks sharing a col range
  float* acc = ws + ((mat == 0) ? WS_QACC : (mat == 1) ? WS_KACC : WS_VACC)
                  + (rep << 12);
  int t = threadIdx.x;
  int j = (g << 10) + (t << 2);
  float ax = 0.f, ay = 0.f, az = 0.f, aw = 0.f;
  int i0 = chunk << 7;
  #pragma unroll 8
  for (int r = 0; r < 128; ++r) {
    int i = i0 + r;
    float xi = x[i];
    const fv4 w4 = ntload4(W + (size_t)i * E + j);
    ax += xi * w4.x; ay += xi * w4.y; az += xi * w4.z; aw += xi * w4.w;
  }
  atomicAdd(acc + j + 0, ax);
  atomicAdd(acc + j + 1, ay);
  atomicAdd(acc + j + 2, az);
  atomicAdd(acc + j + 3, aw);
}

// ---------------- K2: fused k+v shift + logits + accumulation ---------------
// Identical to R6 (183 us baseline) except: slot loads and cache stores are
// PLAIN (L2-allocating) instead of nontemporal. Stores then drain lazily via
// L2 writeback instead of back-pressuring the VMEM queue; loads re-use L3.
#define SLOTS 16
__device__ __forceinline__ void load_slot(int o, int t,
    const float* __restrict__ kin, const float* __restrict__ vin,
    const float* __restrict__ ws, const float* __restrict__ bk,
    const float* __restrict__ bv, fv4 k4[4], fv4 v4[4]) {
  if (o < L - 1) {
    const float* ks = kin + (size_t)(o + 1) * E;
    const float* vs = vin + (size_t)(o + 1) * E;
    #pragma unroll
    for (int c = 0; c < 4; ++c) {
      int e = (c << 10) + (t << 2);
      k4[c] = *reinterpret_cast<const fv4*>(ks + e);
      v4[c] = *reinterpret_cast<const fv4*>(vs + e);
    }
  } else {
    #pragma unroll
    for (int c = 0; c < 4; ++c) {
      int e = (c << 10) + (t << 2);
      fv4 ka = *reinterpret_cast<const fv4*>(ws + WS_KACC + e);
      fv4 va = *reinterpret_cast<const fv4*>(ws + WS_VACC + e);
      #pragma unroll
      for (int r = 1; r < 4; ++r) {
        ka += *reinterpret_cast<const fv4*>(ws + WS_KACC + (r << 12) + e);
        va += *reinterpret_cast<const fv4*>(ws + WS_VACC + (r << 12) + e);
      }
      k4[c] = ka + *reinterpret_cast<const fv4*>(bk + e);
      v4[c] = va + *reinterpret_cast<const fv4*>(bv + e);
    }
  }
}

__global__ __launch_bounds__(256) void kvpass(const float* __restrict__ kin,
    const float* __restrict__ vin,
    const float* __restrict__ bq, const float* __restrict__ bk,
    const float* __restrict__ bv,
    float* __restrict__ kout, float* __restrict__ vout,
    float* __restrict__ ws) {
  __shared__ float wlds[SLOTS * 32];
  __shared__ int flags[SLOTS];
  int t = threadIdx.x;
  if (t < SLOTS) flags[t] = 0;
  // q in registers: sum of 4 replicas + bias
  fv4 q4[4];
  #pragma unroll
  for (int c = 0; c < 4; ++c) {
    int e = (c << 10) + (t << 2);
    fv4 qa = *reinterpret_cast<const fv4*>(ws + WS_QACC + e);
    #pragma unroll
    for (int r = 1; r < 4; ++r)
      qa += *reinterpret_cast<const fv4*>(ws + WS_QACC + (r << 12) + e);
    q4[c] = qa + *reinterpret_cast<const fv4*>(bq + e);
  }
  __syncthreads();   // flags init visible

  float accx[4] = {0,0,0,0}, accy[4] = {0,0,0,0};
  float accz[4] = {0,0,0,0}, accw[4] = {0,0,0,0};
  int base = blockIdx.x * SLOTS;
  int rep = blockIdx.x & 15;

  fv4 kc[4], vc[4], kn[4], vn[4];
  load_slot(base, t, kin, vin, ws, bk, bv, kc, vc);

  for (int s = 0; s < SLOTS; ++s) {
    int o = base + s;
    if (s + 1 < SLOTS)
      load_slot(o + 1, t, kin, vin, ws, bk, bv, kn, vn);
    float* kd = kout + (size_t)o * E;
    float* vd = vout + (size_t)o * E;
    #pragma unroll
    for (int c = 0; c < 4; ++c) {
      int e = (c << 10) + (t << 2);
      *reinterpret_cast<fv4*>(kd + e) = kc[c];
      *reinterpret_cast<fv4*>(vd + e) = vc[c];
    }
    bool nz = false;
    #pragma unroll
    for (int c = 0; c < 4; ++c) {
      float pp = kc[c].x * q4[c].x + kc[c].y * q4[c].y +
                 kc[c].z * q4[c].z + kc[c].w * q4[c].w;
      #pragma unroll
      for (int off = 16; off >= 1; off >>= 1)
        pp += __shfl_xor(pp, off);   // head h = c*8 + (t>>5), dot over 32 lanes
      float w = __expf(pp * SCALE);
      accx[c] += w * vc[c].x; accy[c] += w * vc[c].y;
      accz[c] += w * vc[c].z; accw[c] += w * vc[c].w;
      if ((t & 31) == 0) wlds[(s << 5) + (c << 3) + (t >> 5)] = w;
      nz = nz || vc[c].x != 0.f || vc[c].y != 0.f || vc[c].z != 0.f || vc[c].w != 0.f;
    }
    unsigned long long b = __ballot(nz);
    if ((t & 63) == 0 && b != 0ULL) atomicOr(&flags[s], 1);
    #pragma unroll
    for (int c = 0; c < 4; ++c) { kc[c] = kn[c]; vc[c] = vn[c]; }
  }
  float* num = ws + WS_NUMP + (rep << 12);
  #pragma unroll
  for (int c = 0; c < 4; ++c) {
    int e = (c << 10) + (t << 2);
    atomicAdd(num + e + 0, accx[c]);
    atomicAdd(num + e + 1, accy[c]);
    atomicAdd(num + e + 2, accz[c]);
    atomicAdd(num + e + 3, accw[c]);
  }
  __syncthreads();   // wlds + flags complete
  if (t < 32) {
    float d = 0.f;
    #pragma unroll
    for (int s = 0; s < SLOTS; ++s)
      if (flags[s]) d += wlds[(s << 5) + t];
    atomicAdd(ws + WS_DENP + (rep << 6) + t, d);
  }
}

// ---------------- K3: sum the 16 replicas ----------------------------------
__global__ __launch_bounds__(256) void merge(float* __restrict__ ws) {
  int e = blockIdx.x * 256 + threadIdx.x;   // 16 blocks
  float s = 0.f;
  #pragma unroll
  for (int r = 0; r < 16; ++r) s += ws[WS_NUMP + (r << 12) + e];
  ws[WS_NUM + e] = s;
  if (e < 64) {
    float d = 0.f;
    #pragma unroll
    for (int r = 0; r < 16; ++r) d += ws[WS_DENP + (r << 6) + e];
    ws[WS_DEN + e] = d;
  }
}

// ---------------- K4: output GEMV (values = num/den on the fly) -------------
__global__ __launch_bounds__(256) void gemv_out(const float* __restrict__ Wo,
    const float* __restrict__ bo, float* __restrict__ ws) {
  int b = blockIdx.x;            // 256 blocks: 64 i-chunks x 4 col-groups
  int chunk = b >> 2;
  int g = b & 3;
  int t = threadIdx.x;
  int j = (g << 10) + (t << 2);
  const float* num = ws + WS_NUM;
  const float* den = ws + WS_DEN;
  __shared__ float vals[64];
  int i0 = chunk << 6;
  if (t < 64) vals[t] = num[i0 + t] / den[(i0 + t) >> 7];
  __syncthreads();
  float ax = 0.f, ay = 0.f, az = 0.f, aw = 0.f;
  #pragma unroll 4
  for (int r = 0; r < 64; ++r) {
    int i = i0 + r;
    float vi = vals[r];
    const fv4 w4 = ntload4(Wo + (size_t)i * E + j);
    ax += vi * w4.x; ay += vi * w4.y; az += vi * w4.z; aw += vi * w4.w;
  }
  if (chunk == 0) {
    const fv4 b4 = *reinterpret_cast<const fv4*>(bo + j);
    ax += b4.x; ay += b4.y; az += b4.z; aw += b4.w;
  }
  float* oacc = ws + WS_OACC;
  atomicAdd(oacc + j + 0, ax);
  atomicAdd(oacc + j + 1, ay);
  atomicAdd(oacc + j + 2, az);
  atomicAdd(oacc + j + 3, aw);
}

// ---------------- K5: final store of out_i ----------------------------------
__global__ __launch_bounds__(256) void writeout(const float* __restrict__ ws,
                                                float* __restrict__ out) {
  int i = blockIdx.x * 256 + threadIdx.x;
  out[i] = ws[WS_OACC + i];
}

extern "C" void kernel_launch(void* const* d_in, const int* in_sizes, int n_in,
                              void* d_out, int out_size, void* d_ws, size_t ws_size,
                              hipStream_t stream) {
  const float* x   = (const float*)d_in[0];
  const float* vin = (const float*)d_in[1];
  const float* kin = (const float*)d_in[2];
  const float* Wv  = (const float*)d_in[3];
  const float* bv  = (const float*)d_in[4];
  const float* Wq  = (const float*)d_in[5];
  const float* bq  = (const float*)d_in[6];
  const float* Wk  = (const float*)d_in[7];
  const float* bk  = (const float*)d_in[8];
  const float* Wo  = (const float*)d_in[9];
  const float* bo  = (const float*)d_in[10];
  float* out  = (float*)d_out;
  float* vout = out + E;
  float* kout = vout + (size_t)L * E;
  float* ws   = (float*)d_ws;

  zero_ws<<<(WS_ZERO_FLOATS + 255) / 256, 256, 0, stream>>>(ws);
  gemv_qkv<<<384, 256, 0, stream>>>(x, Wq, Wk, Wv, ws);
  kvpass<<<L / SLOTS, 256, 0, stream>>>(kin, vin, bq, bk, bv, kout, vout, ws);
  merge<<<16, 256, 0, stream>>>(ws);
  gemv_out<<<256, 256, 0, stream>>>(Wo, bo, ws);
  writeout<<<16, 256, 0, stream>>>(ws, out);
}

// Round 11
// 187.887 us; speedup vs baseline: 1.0880x; 1.0880x over previous
//
#include <hip/hip_runtime.h>

#define E 4096
#define H 32
#define L 8192
#define SCALE 0.08838834764831845f  // 1/sqrt(128)

// workspace layout (float offsets)
#define WS_QACC 0                 // 4 reps x 4096
#define WS_KACC 16384             // 4 reps x 4096
#define WS_VACC 32768             // 4 reps x 4096
#define WS_OACC 49152             // 4096
#define WS_NUMP 53248             // 16 reps x 4096
#define WS_DENP 118784            // 16 reps x 64
#define WS_NUM  119808            // 4096
#define WS_DEN  123904            // 64
#define WS_ZERO_FLOATS 123968

typedef float fv4 __attribute__((ext_vector_type(4)));

__device__ __forceinline__ fv4 ntload4(const float* p) {
  return __builtin_nontemporal_load(reinterpret_cast<const fv4*>(p));
}
__device__ __forceinline__ void ntstore4(float* p, fv4 v) {
  __builtin_nontemporal_store(v, reinterpret_cast<fv4*>(p));
}

// ---------------- K0: zero accumulator region -------------------------------
__global__ __launch_bounds__(256) void zero_ws(float* __restrict__ ws) {
  int i = blockIdx.x * 256 + threadIdx.x;
  if (i < WS_ZERO_FLOATS) ws[i] = 0.f;
}

// ---------------- K1: fused q/k/v GEMV (split-K, replicated partials) -------
__global__ __launch_bounds__(256) void gemv_qkv(const float* __restrict__ x,
    const float* __restrict__ Wq, const float* __restrict__ Wk,
    const float* __restrict__ Wv, float* __restrict__ ws) {
  int b = blockIdx.x;            // 384 blocks: 3 mats x 32 chunks x 4 col-groups
  int mat = b >> 7;
  int rem = b & 127;
  int chunk = rem >> 2;          // 32 chunks of 128 rows
  int g = rem & 3;               // 4 col groups of 1024
  const float* W = (mat == 0) ? Wq : (mat == 1) ? Wk : Wv;
  int rep = (b >> 2) & 3;
  float* acc = ws + ((mat == 0) ? WS_QACC : (mat == 1) ? WS_KACC : WS_VACC)
                  + (rep << 12);
  int t = threadIdx.x;
  int j = (g << 10) + (t << 2);
  float ax = 0.f, ay = 0.f, az = 0.f, aw = 0.f;
  int i0 = chunk << 7;
  #pragma unroll 8
  for (int r = 0; r < 128; ++r) {
    int i = i0 + r;
    float xi = x[i];
    const fv4 w4 = ntload4(W + (size_t)i * E + j);
    ax += xi * w4.x; ay += xi * w4.y; az += xi * w4.z; aw += xi * w4.w;
  }
  atomicAdd(acc + j + 0, ax);
  atomicAdd(acc + j + 1, ay);
  atomicAdd(acc + j + 2, az);
  atomicAdd(acc + j + 3, aw);
}

// ---------------- K2: two-phase k/v shift + logits + accumulation -----------
// R6 geometry (512 blocks x 16 slots, NT, 16-rep atomics) but the slot loop is
// split into phase K (kin->kout + logits -> wlds) and phase V (vin->vout +
// mask + accumulate). Each phase touches 2 memory streams instead of 4.
#define SLOTS 16

__device__ __forceinline__ void load_k(int o, int t,
    const float* __restrict__ kin, const float* __restrict__ ws,
    const float* __restrict__ bk, fv4 k4[4]) {
  if (o < L - 1) {
    const float* ks = kin + (size_t)(o + 1) * E;
    #pragma unroll
    for (int c = 0; c < 4; ++c)
      k4[c] = ntload4(ks + (c << 10) + (t << 2));
  } else {
    #pragma unroll
    for (int c = 0; c < 4; ++c) {
      int e = (c << 10) + (t << 2);
      fv4 ka = *reinterpret_cast<const fv4*>(ws + WS_KACC + e);
      #pragma unroll
      for (int r = 1; r < 4; ++r)
        ka += *reinterpret_cast<const fv4*>(ws + WS_KACC + (r << 12) + e);
      k4[c] = ka + *reinterpret_cast<const fv4*>(bk + e);
    }
  }
}

__device__ __forceinline__ void load_v(int o, int t,
    const float* __restrict__ vin, const float* __restrict__ ws,
    const float* __restrict__ bv, fv4 v4[4]) {
  if (o < L - 1) {
    const float* vs = vin + (size_t)(o + 1) * E;
    #pragma unroll
    for (int c = 0; c < 4; ++c)
      v4[c] = ntload4(vs + (c << 10) + (t << 2));
  } else {
    #pragma unroll
    for (int c = 0; c < 4; ++c) {
      int e = (c << 10) + (t << 2);
      fv4 va = *reinterpret_cast<const fv4*>(ws + WS_VACC + e);
      #pragma unroll
      for (int r = 1; r < 4; ++r)
        va += *reinterpret_cast<const fv4*>(ws + WS_VACC + (r << 12) + e);
      v4[c] = va + *reinterpret_cast<const fv4*>(bv + e);
    }
  }
}

__global__ __launch_bounds__(256) void kvpass(const float* __restrict__ kin,
    const float* __restrict__ vin,
    const float* __restrict__ bq, const float* __restrict__ bk,
    const float* __restrict__ bv,
    float* __restrict__ kout, float* __restrict__ vout,
    float* __restrict__ ws) {
  __shared__ float wlds[SLOTS * 32];
  __shared__ int flags[SLOTS];
  int t = threadIdx.x;
  if (t < SLOTS) flags[t] = 0;
  // q in registers: sum of 4 replicas + bias
  fv4 q4[4];
  #pragma unroll
  for (int c = 0; c < 4; ++c) {
    int e = (c << 10) + (t << 2);
    fv4 qa = *reinterpret_cast<const fv4*>(ws + WS_QACC + e);
    #pragma unroll
    for (int r = 1; r < 4; ++r)
      qa += *reinterpret_cast<const fv4*>(ws + WS_QACC + (r << 12) + e);
    q4[c] = qa + *reinterpret_cast<const fv4*>(bq + e);
  }
  __syncthreads();   // flags init visible

  int base = blockIdx.x * SLOTS;
  int rep = blockIdx.x & 15;

  // ---------------- phase K: kin -> kout, logits -> wlds ----------------
  {
    fv4 kc[4], kn[4];
    load_k(base, t, kin, ws, bk, kc);
    for (int s = 0; s < SLOTS; ++s) {
      int o = base + s;
      if (s + 1 < SLOTS) load_k(o + 1, t, kin, ws, bk, kn);
      float* kd = kout + (size_t)o * E;
      #pragma unroll
      for (int c = 0; c < 4; ++c)
        ntstore4(kd + (c << 10) + (t << 2), kc[c]);
      #pragma unroll
      for (int c = 0; c < 4; ++c) {
        float pp = kc[c].x * q4[c].x + kc[c].y * q4[c].y +
                   kc[c].z * q4[c].z + kc[c].w * q4[c].w;
        #pragma unroll
        for (int off = 16; off >= 1; off >>= 1)
          pp += __shfl_xor(pp, off);   // head h = c*8 + (t>>5)
        if ((t & 31) == 0)
          wlds[(s << 5) + (c << 3) + (t >> 5)] = __expf(pp * SCALE);
      }
      #pragma unroll
      for (int c = 0; c < 4; ++c) kc[c] = kn[c];
    }
  }
  __syncthreads();   // wlds visible to all

  // ---------------- phase V: vin -> vout, mask + accumulate -------------
  float accx[4] = {0,0,0,0}, accy[4] = {0,0,0,0};
  float accz[4] = {0,0,0,0}, accw[4] = {0,0,0,0};
  {
    fv4 vc[4], vn[4];
    load_v(base, t, vin, ws, bv, vc);
    for (int s = 0; s < SLOTS; ++s) {
      int o = base + s;
      if (s + 1 < SLOTS) load_v(o + 1, t, vin, ws, bv, vn);
      float* vd = vout + (size_t)o * E;
      #pragma unroll
      for (int c = 0; c < 4; ++c)
        ntstore4(vd + (c << 10) + (t << 2), vc[c]);
      bool nz = false;
      #pragma unroll
      for (int c = 0; c < 4; ++c) {
        float w = wlds[(s << 5) + (c << 3) + (t >> 5)];   // broadcast read
        accx[c] += w * vc[c].x; accy[c] += w * vc[c].y;
        accz[c] += w * vc[c].z; accw[c] += w * vc[c].w;
        nz = nz || vc[c].x != 0.f || vc[c].y != 0.f ||
             vc[c].z != 0.f || vc[c].w != 0.f;
      }
      unsigned long long b = __ballot(nz);
      if ((t & 63) == 0 && b != 0ULL) atomicOr(&flags[s], 1);
      #pragma unroll
      for (int c = 0; c < 4; ++c) vc[c] = vn[c];
    }
  }
  float* num = ws + WS_NUMP + (rep << 12);
  #pragma unroll
  for (int c = 0; c < 4; ++c) {
    int e = (c << 10) + (t << 2);
    atomicAdd(num + e + 0, accx[c]);
    atomicAdd(num + e + 1, accy[c]);
    atomicAdd(num + e + 2, accz[c]);
    atomicAdd(num + e + 3, accw[c]);
  }
  __syncthreads();   // flags complete
  if (t < 32) {
    float d = 0.f;
    #pragma unroll
    for (int s = 0; s < SLOTS; ++s)
      if (flags[s]) d += wlds[(s << 5) + t];
    atomicAdd(ws + WS_DENP + (rep << 6) + t, d);
  }
}

// ---------------- K3: sum the 16 replicas ----------------------------------
__global__ __launch_bounds__(256) void merge(float* __restrict__ ws) {
  int e = blockIdx.x * 256 + threadIdx.x;   // 16 blocks
  float s = 0.f;
  #pragma unroll
  for (int r = 0; r < 16; ++r) s += ws[WS_NUMP + (r << 12) + e];
  ws[WS_NUM + e] = s;
  if (e < 64) {
    float d = 0.f;
    #pragma unroll
    for (int r = 0; r < 16; ++r) d += ws[WS_DENP + (r << 6) + e];
    ws[WS_DEN + e] = d;
  }
}

// ---------------- K4: output GEMV (values = num/den on the fly) -------------
__global__ __launch_bounds__(256) void gemv_out(const float* __restrict__ Wo,
    const float* __restrict__ bo, float* __restrict__ ws) {
  int b = blockIdx.x;            // 256 blocks: 64 i-chunks x 4 col-groups
  int chunk = b >> 2;
  int g = b & 3;
  int t = threadIdx.x;
  int j = (g << 10) + (t << 2);
  const float* num = ws + WS_NUM;
  const float* den = ws + WS_DEN;
  __shared__ float vals[64];
  int i0 = chunk << 6;
  if (t < 64) vals[t] = num[i0 + t] / den[(i0 + t) >> 7];
  __syncthreads();
  float ax = 0.f, ay = 0.f, az = 0.f, aw = 0.f;
  #pragma unroll 4
  for (int r = 0; r < 64; ++r) {
    int i = i0 + r;
    float vi = vals[r];
    const fv4 w4 = ntload4(Wo + (size_t)i * E + j);
    ax += vi * w4.x; ay += vi * w4.y; az += vi * w4.z; aw += vi * w4.w;
  }
  if (chunk == 0) {
    const fv4 b4 = *reinterpret_cast<const fv4*>(bo + j);
    ax += b4.x; ay += b4.y; az += b4.z; aw += b4.w;
  }
  float* oacc = ws + WS_OACC;
  atomicAdd(oacc + j + 0, ax);
  atomicAdd(oacc + j + 1, ay);
  atomicAdd(oacc + j + 2, az);
  atomicAdd(oacc + j + 3, aw);
}

// ---------------- K5: final store of out_i ----------------------------------
__global__ __launch_bounds__(256) void writeout(const float* __restrict__ ws,
                                                float* __restrict__ out) {
  int i = blockIdx.x * 256 + threadIdx.x;
  out[i] = ws[WS_OACC + i];
}

extern "C" void kernel_launch(void* const* d_in, const int* in_sizes, int n_in,
                              void* d_out, int out_size, void* d_ws, size_t ws_size,
                              hipStream_t stream) {
  const float* x   = (const float*)d_in[0];
  const float* vin = (const float*)d_in[1];
  const float* kin = (const float*)d_in[2];
  const float* Wv  = (const float*)d_in[3];
  const float* bv  = (const float*)d_in[4];
  const float* Wq  = (const float*)d_in[5];
  const float* bq  = (const float*)d_in[6];
  const float* Wk  = (const float*)d_in[7];
  const float* bk  = (const float*)d_in[8];
  const float* Wo  = (const float*)d_in[9];
  const float* bo  = (const float*)d_in[10];
  float* out  = (float*)d_out;
  float* vout = out + E;
  float* kout = vout + (size_t)L * E;
  float* ws   = (float*)d_ws;

  zero_ws<<<(WS_ZERO_FLOATS + 255) / 256, 256, 0, stream>>>(ws);
  gemv_qkv<<<384, 256, 0, stream>>>(x, Wq, Wk, Wv, ws);
  kvpass<<<L / SLOTS, 256, 0, stream>>>(kin, vin, bq, bk, bv, kout, vout, ws);
  merge<<<16, 256, 0, stream>>>(ws);
  gemv_out<<<256, 256, 0, stream>>>(Wo, bo, ws);
  writeout<<<16, 256, 0, stream>>>(ws, out);
}

// Round 12
// 184.376 us; speedup vs baseline: 1.1087x; 1.0190x over previous
//
#include <hip/hip_runtime.h>

#define E 4096
#define H 32
#define L 8192
#define SCALE 0.08838834764831845f  // 1/sqrt(128)

// workspace layout (float offsets)
#define WS_QACC 0                 // 4 reps x 4096
#define WS_KACC 16384             // 4 reps x 4096
#define WS_VACC 32768             // 4 reps x 4096
#define WS_OACC 49152             // 4096
#define WS_NUMP 53248             // 16 reps x 4096
#define WS_DENP 118784            // 16 reps x 64
#define WS_NUM  119808            // 4096
#define WS_DEN  123904            // 64
#define WS_ZERO_FLOATS 123968

typedef float fv4 __attribute__((ext_vector_type(4)));

__device__ __forceinline__ fv4 ntload4(const float* p) {
  return __builtin_nontemporal_load(reinterpret_cast<const fv4*>(p));
}
__device__ __forceinline__ void ntstore4(float* p, fv4 v) {
  __builtin_nontemporal_store(v, reinterpret_cast<fv4*>(p));
}

// ---------------- K0: zero accumulator region -------------------------------
__global__ __launch_bounds__(256) void zero_ws(float* __restrict__ ws) {
  int i = blockIdx.x * 256 + threadIdx.x;
  if (i < WS_ZERO_FLOATS) ws[i] = 0.f;
}

// ---------------- K1: fused q/k/v GEMV (split-K, replicated partials) -------
__global__ __launch_bounds__(256) void gemv_qkv(const float* __restrict__ x,
    const float* __restrict__ Wq, const float* __restrict__ Wk,
    const float* __restrict__ Wv, float* __restrict__ ws) {
  int b = blockIdx.x;            // 384 blocks: 3 mats x 32 chunks x 4 col-groups
  int mat = b >> 7;
  int rem = b & 127;
  int chunk = rem >> 2;          // 32 chunks of 128 rows
  int g = rem & 3;               // 4 col groups of 1024
  const float* W = (mat == 0) ? Wq : (mat == 1) ? Wk : Wv;
  int rep = (b >> 2) & 3;
  float* acc = ws + ((mat == 0) ? WS_QACC : (mat == 1) ? WS_KACC : WS_VACC)
                  + (rep << 12);
  int t = threadIdx.x;
  int j = (g << 10) + (t << 2);
  float ax = 0.f, ay = 0.f, az = 0.f, aw = 0.f;
  int i0 = chunk << 7;
  #pragma unroll 8
  for (int r = 0; r < 128; ++r) {
    int i = i0 + r;
    float xi = x[i];
    const fv4 w4 = ntload4(W + (size_t)i * E + j);
    ax += xi * w4.x; ay += xi * w4.y; az += xi * w4.z; aw += xi * w4.w;
  }
  atomicAdd(acc + j + 0, ax);
  atomicAdd(acc + j + 1, ay);
  atomicAdd(acc + j + 2, az);
  atomicAdd(acc + j + 3, aw);
}

// ---------------- K2: fused k+v shift + logits + accumulation ---------------
// R6 kernel with STRIDED slot mapping: block b handles slots {b, b+512, ...}.
// At each step the 512 blocks collectively sweep one contiguous 8 MB window
// per stream (m13 copy-like locality) instead of 512 scattered 16 KB windows.
#define SLOTS 16
#define NBLK  512
__device__ __forceinline__ void load_slot(int o, int t,
    const float* __restrict__ kin, const float* __restrict__ vin,
    const float* __restrict__ ws, const float* __restrict__ bk,
    const float* __restrict__ bv, fv4 k4[4], fv4 v4[4]) {
  if (o < L - 1) {
    const float* ks = kin + (size_t)(o + 1) * E;
    const float* vs = vin + (size_t)(o + 1) * E;
    #pragma unroll
    for (int c = 0; c < 4; ++c) {
      int e = (c << 10) + (t << 2);
      k4[c] = ntload4(ks + e);
      v4[c] = ntload4(vs + e);
    }
  } else {
    #pragma unroll
    for (int c = 0; c < 4; ++c) {
      int e = (c << 10) + (t << 2);
      fv4 ka = *reinterpret_cast<const fv4*>(ws + WS_KACC + e);
      fv4 va = *reinterpret_cast<const fv4*>(ws + WS_VACC + e);
      #pragma unroll
      for (int r = 1; r < 4; ++r) {
        ka += *reinterpret_cast<const fv4*>(ws + WS_KACC + (r << 12) + e);
        va += *reinterpret_cast<const fv4*>(ws + WS_VACC + (r << 12) + e);
      }
      k4[c] = ka + *reinterpret_cast<const fv4*>(bk + e);
      v4[c] = va + *reinterpret_cast<const fv4*>(bv + e);
    }
  }
}

__global__ __launch_bounds__(256) void kvpass(const float* __restrict__ kin,
    const float* __restrict__ vin,
    const float* __restrict__ bq, const float* __restrict__ bk,
    const float* __restrict__ bv,
    float* __restrict__ kout, float* __restrict__ vout,
    float* __restrict__ ws) {
  __shared__ float wlds[SLOTS * 32];
  __shared__ int flags[SLOTS];
  int t = threadIdx.x;
  if (t < SLOTS) flags[t] = 0;
  // q in registers: sum of 4 replicas + bias
  fv4 q4[4];
  #pragma unroll
  for (int c = 0; c < 4; ++c) {
    int e = (c << 10) + (t << 2);
    fv4 qa = *reinterpret_cast<const fv4*>(ws + WS_QACC + e);
    #pragma unroll
    for (int r = 1; r < 4; ++r)
      qa += *reinterpret_cast<const fv4*>(ws + WS_QACC + (r << 12) + e);
    q4[c] = qa + *reinterpret_cast<const fv4*>(bq + e);
  }
  __syncthreads();   // flags init visible

  float accx[4] = {0,0,0,0}, accy[4] = {0,0,0,0};
  float accz[4] = {0,0,0,0}, accw[4] = {0,0,0,0};
  int base = blockIdx.x;         // strided mapping: o = base + s*NBLK
  int rep = blockIdx.x & 15;

  fv4 kc[4], vc[4], kn[4], vn[4];
  load_slot(base, t, kin, vin, ws, bk, bv, kc, vc);

  for (int s = 0; s < SLOTS; ++s) {
    int o = base + s * NBLK;
    if (s + 1 < SLOTS)
      load_slot(o + NBLK, t, kin, vin, ws, bk, bv, kn, vn);
    float* kd = kout + (size_t)o * E;
    float* vd = vout + (size_t)o * E;
    #pragma unroll
    for (int c = 0; c < 4; ++c) {
      int e = (c << 10) + (t << 2);
      ntstore4(kd + e, kc[c]);
      ntstore4(vd + e, vc[c]);
    }
    bool nz = false;
    #pragma unroll
    for (int c = 0; c < 4; ++c) {
      float pp = kc[c].x * q4[c].x + kc[c].y * q4[c].y +
                 kc[c].z * q4[c].z + kc[c].w * q4[c].w;
      #pragma unroll
      for (int off = 16; off >= 1; off >>= 1)
        pp += __shfl_xor(pp, off);   // head h = c*8 + (t>>5), dot over 32 lanes
      float w = __expf(pp * SCALE);
      accx[c] += w * vc[c].x; accy[c] += w * vc[c].y;
      accz[c] += w * vc[c].z; accw[c] += w * vc[c].w;
      if ((t & 31) == 0) wlds[(s << 5) + (c << 3) + (t >> 5)] = w;
      nz = nz || vc[c].x != 0.f || vc[c].y != 0.f || vc[c].z != 0.f || vc[c].w != 0.f;
    }
    unsigned long long b = __ballot(nz);
    if ((t & 63) == 0 && b != 0ULL) atomicOr(&flags[s], 1);
    #pragma unroll
    for (int c = 0; c < 4; ++c) { kc[c] = kn[c]; vc[c] = vn[c]; }
  }
  float* num = ws + WS_NUMP + (rep << 12);
  #pragma unroll
  for (int c = 0; c < 4; ++c) {
    int e = (c << 10) + (t << 2);
    atomicAdd(num + e + 0, accx[c]);
    atomicAdd(num + e + 1, accy[c]);
    atomicAdd(num + e + 2, accz[c]);
    atomicAdd(num + e + 3, accw[c]);
  }
  __syncthreads();   // wlds + flags complete
  if (t < 32) {
    float d = 0.f;
    #pragma unroll
    for (int s = 0; s < SLOTS; ++s)
      if (flags[s]) d += wlds[(s << 5) + t];
    atomicAdd(ws + WS_DENP + (rep << 6) + t, d);
  }
}

// ---------------- K3: sum the 16 replicas ----------------------------------
__global__ __launch_bounds__(256) void merge(float* __restrict__ ws) {
  int e = blockIdx.x * 256 + threadIdx.x;   // 16 blocks
  float s = 0.f;
  #pragma unroll
  for (int r = 0; r < 16; ++r) s += ws[WS_NUMP + (r << 12) + e];
  ws[WS_NUM + e] = s;
  if (e < 64) {
    float d = 0.f;
    #pragma unroll
    for (int r = 0; r < 16; ++r) d += ws[WS_DENP + (r << 6) + e];
    ws[WS_DEN + e] = d;
  }
}

// ---------------- K4: output GEMV (values = num/den on the fly) -------------
__global__ __launch_bounds__(256) void gemv_out(const float* __restrict__ Wo,
    const float* __restrict__ bo, float* __restrict__ ws) {
  int b = blockIdx.x;            // 256 blocks: 64 i-chunks x 4 col-groups
  int chunk = b >> 2;
  int g = b & 3;
  int t = threadIdx.x;
  int j = (g << 10) + (t << 2);
  const float* num = ws + WS_NUM;
  const float* den = ws + WS_DEN;
  __shared__ float vals[64];
  int i0 = chunk << 6;
  if (t < 64) vals[t] = num[i0 + t] / den[(i0 + t) >> 7];
  __syncthreads();
  float ax = 0.f, ay = 0.f, az = 0.f, aw = 0.f;
  #pragma unroll 4
  for (int r = 0; r < 64; ++r) {
    int i = i0 + r;
    float vi = vals[r];
    const fv4 w4 = ntload4(Wo + (size_t)i * E + j);
    ax += vi * w4.x; ay += vi * w4.y; az += vi * w4.z; aw += vi * w4.w;
  }
  if (chunk == 0) {
    const fv4 b4 = *reinterpret_cast<const fv4*>(bo + j);
    ax += b4.x; ay += b4.y; az += b4.z; aw += b4.w;
  }
  float* oacc = ws + WS_OACC;
  atomicAdd(oacc + j + 0, ax);
  atomicAdd(oacc + j + 1, ay);
  atomicAdd(oacc + j + 2, az);
  atomicAdd(oacc + j + 3, aw);
}

// ---------------- K5: final store of out_i ----------------------------------
__global__ __launch_bounds__(256) void writeout(const float* __restrict__ ws,
                                                float* __restrict__ out) {
  int i = blockIdx.x * 256 + threadIdx.x;
  out[i] = ws[WS_OACC + i];
}

extern "C" void kernel_launch(void* const* d_in, const int* in_sizes, int n_in,
                              void* d_out, int out_size, void* d_ws, size_t ws_size,
                              hipStream_t stream) {
  const float* x   = (const float*)d_in[0];
  const float* vin = (const float*)d_in[1];
  const float* kin = (const float*)d_in[2];
  const float* Wv  = (const float*)d_in[3];
  const float* bv  = (const float*)d_in[4];
  const float* Wq  = (const float*)d_in[5];
  const float* bq  = (const float*)d_in[6];
  const float* Wk  = (const float*)d_in[7];
  const float* bk  = (const float*)d_in[8];
  const float* Wo  = (const float*)d_in[9];
  const float* bo  = (const float*)d_in[10];
  float* out  = (float*)d_out;
  float* vout = out + E;
  float* kout = vout + (size_t)L * E;
  float* ws   = (float*)d_ws;

  zero_ws<<<(WS_ZERO_FLOATS + 255) / 256, 256, 0, stream>>>(ws);
  gemv_qkv<<<384, 256, 0, stream>>>(x, Wq, Wk, Wv, ws);
  kvpass<<<NBLK, 256, 0, stream>>>(kin, vin, bq, bk, bv, kout, vout, ws);
  merge<<<16, 256, 0, stream>>>(ws);
  gemv_out<<<256, 256, 0, stream>>>(Wo, bo, ws);
  writeout<<<16, 256, 0, stream>>>(ws, out);
}

// Round 13
// 176.254 us; speedup vs baseline: 1.1598x; 1.0461x over previous
//
#include <hip/hip_runtime.h>

#define E 4096
#define H 32
#define L 8192
#define SCALE 0.08838834764831845f  // 1/sqrt(128)

// workspace layout (float offsets); total 734208 floats = 2.9 MB
#define WS_PART  0            // [3][32][4096] exclusive qkv partials
#define WS_QFIN  393216       // 4096 (bias included)
#define WS_KFIN  397312       // 4096 (bias included)
#define WS_VFIN  401408       // 4096 (bias included)
#define WS_NUMP  405504       // 16 reps x 4096 (zeroed)
#define WS_DENP  471040       // 16 reps x 64   (zeroed)
#define WS_OPART 472064       // [64][4096] exclusive gemv_out partials

typedef float fv4 __attribute__((ext_vector_type(4)));

__device__ __forceinline__ fv4 ntload4(const float* p) {
  return __builtin_nontemporal_load(reinterpret_cast<const fv4*>(p));
}
__device__ __forceinline__ void ntstore4(float* p, fv4 v) {
  __builtin_nontemporal_store(v, reinterpret_cast<fv4*>(p));
}

// ---------------- K0: zero NUMP/DENP only (66560 floats) --------------------
__global__ __launch_bounds__(256) void zero_np(float* __restrict__ ws) {
  int i = blockIdx.x * 256 + threadIdx.x;
  if (i < (WS_OPART - WS_NUMP)) ws[WS_NUMP + i] = 0.f;
}

// ---------------- K1: q/k/v GEMV, exclusive NT partials (no atomics) --------
__global__ __launch_bounds__(256) void gemv_qkv(const float* __restrict__ x,
    const float* __restrict__ Wq, const float* __restrict__ Wk,
    const float* __restrict__ Wv, float* __restrict__ ws) {
  int b = blockIdx.x;            // 384 blocks: 3 mats x 32 chunks x 4 col-groups
  int mat = b >> 7;
  int rem = b & 127;
  int chunk = rem >> 2;          // 32 chunks of 128 rows
  int g = rem & 3;               // 4 col groups of 1024
  const float* W = (mat == 0) ? Wq : (mat == 1) ? Wk : Wv;
  int t = threadIdx.x;
  int j = (g << 10) + (t << 2);
  float ax = 0.f, ay = 0.f, az = 0.f, aw = 0.f;
  int i0 = chunk << 7;
  #pragma unroll 8
  for (int r = 0; r < 128; ++r) {
    int i = i0 + r;
    float xi = x[i];
    const fv4 w4 = ntload4(W + (size_t)i * E + j);
    ax += xi * w4.x; ay += xi * w4.y; az += xi * w4.z; aw += xi * w4.w;
  }
  fv4 val = {ax, ay, az, aw};
  ntstore4(ws + WS_PART + (mat << 17) + (chunk << 12) + j, val);
}

// ---------------- K2: reduce 32 chunk-partials, fold in biases --------------
__global__ __launch_bounds__(256) void qkvred(const float* __restrict__ bq,
    const float* __restrict__ bk, const float* __restrict__ bv,
    float* __restrict__ ws) {
  int e = blockIdx.x * 256 + threadIdx.x;   // 48 blocks, e in [0,12288)
  int mat = e >> 12;
  int col = e & 4095;
  const float* part = ws + WS_PART + (mat << 17);
  float s = 0.f;
  #pragma unroll 8
  for (int c = 0; c < 32; ++c) s += part[(c << 12) + col];
  const float* bias = (mat == 0) ? bq : (mat == 1) ? bk : bv;
  ws[WS_QFIN + (mat << 12) + col] = s + bias[col];
}

// ---------------- K3: fused k+v shift + logits + accumulation (R6 verbatim) -
#define SLOTS 16
__device__ __forceinline__ void load_slot(int o, int t,
    const float* __restrict__ kin, const float* __restrict__ vin,
    const float* __restrict__ ws, fv4 k4[4], fv4 v4[4]) {
  if (o < L - 1) {
    const float* ks = kin + (size_t)(o + 1) * E;
    const float* vs = vin + (size_t)(o + 1) * E;
    #pragma unroll
    for (int c = 0; c < 4; ++c) {
      int e = (c << 10) + (t << 2);
      k4[c] = ntload4(ks + e);
      v4[c] = ntload4(vs + e);
    }
  } else {
    #pragma unroll
    for (int c = 0; c < 4; ++c) {
      int e = (c << 10) + (t << 2);
      k4[c] = *reinterpret_cast<const fv4*>(ws + WS_KFIN + e);
      v4[c] = *reinterpret_cast<const fv4*>(ws + WS_VFIN + e);
    }
  }
}

__global__ __launch_bounds__(256) void kvpass(const float* __restrict__ kin,
    const float* __restrict__ vin,
    float* __restrict__ kout, float* __restrict__ vout,
    float* __restrict__ ws) {
  __shared__ float wlds[SLOTS * 32];
  __shared__ int flags[SLOTS];
  int t = threadIdx.x;
  if (t < SLOTS) flags[t] = 0;
  // q in registers (bias already folded in by qkvred)
  fv4 q4[4];
  #pragma unroll
  for (int c = 0; c < 4; ++c)
    q4[c] = *reinterpret_cast<const fv4*>(ws + WS_QFIN + (c << 10) + (t << 2));
  __syncthreads();   // flags init visible

  float accx[4] = {0,0,0,0}, accy[4] = {0,0,0,0};
  float accz[4] = {0,0,0,0}, accw[4] = {0,0,0,0};
  int base = blockIdx.x * SLOTS;
  int rep = blockIdx.x & 15;

  fv4 kc[4], vc[4], kn[4], vn[4];
  load_slot(base, t, kin, vin, ws, kc, vc);

  for (int s = 0; s < SLOTS; ++s) {
    int o = base + s;
    if (s + 1 < SLOTS)
      load_slot(o + 1, t, kin, vin, ws, kn, vn);
    float* kd = kout + (size_t)o * E;
    float* vd = vout + (size_t)o * E;
    #pragma unroll
    for (int c = 0; c < 4; ++c) {
      int e = (c << 10) + (t << 2);
      ntstore4(kd + e, kc[c]);
      ntstore4(vd + e, vc[c]);
    }
    bool nz = false;
    #pragma unroll
    for (int c = 0; c < 4; ++c) {
      float pp = kc[c].x * q4[c].x + kc[c].y * q4[c].y +
                 kc[c].z * q4[c].z + kc[c].w * q4[c].w;
      #pragma unroll
      for (int off = 16; off >= 1; off >>= 1)
        pp += __shfl_xor(pp, off);   // head h = c*8 + (t>>5), dot over 32 lanes
      float w = __expf(pp * SCALE);
      accx[c] += w * vc[c].x; accy[c] += w * vc[c].y;
      accz[c] += w * vc[c].z; accw[c] += w * vc[c].w;
      if ((t & 31) == 0) wlds[(s << 5) + (c << 3) + (t >> 5)] = w;
      nz = nz || vc[c].x != 0.f || vc[c].y != 0.f || vc[c].z != 0.f || vc[c].w != 0.f;
    }
    unsigned long long b = __ballot(nz);
    if ((t & 63) == 0 && b != 0ULL) atomicOr(&flags[s], 1);
    #pragma unroll
    for (int c = 0; c < 4; ++c) { kc[c] = kn[c]; vc[c] = vn[c]; }
  }
  float* num = ws + WS_NUMP + (rep << 12);
  #pragma unroll
  for (int c = 0; c < 4; ++c) {
    int e = (c << 10) + (t << 2);
    atomicAdd(num + e + 0, accx[c]);
    atomicAdd(num + e + 1, accy[c]);
    atomicAdd(num + e + 2, accz[c]);
    atomicAdd(num + e + 3, accw[c]);
  }
  __syncthreads();   // wlds + flags complete
  if (t < 32) {
    float d = 0.f;
    #pragma unroll
    for (int s = 0; s < SLOTS; ++s)
      if (flags[s]) d += wlds[(s << 5) + t];
    atomicAdd(ws + WS_DENP + (rep << 6) + t, d);
  }
}

// ---------------- K4: output GEMV with merge folded in; exclusive partials --
__global__ __launch_bounds__(256) void gemv_out(const float* __restrict__ Wo,
    const float* __restrict__ bo, float* __restrict__ ws) {
  int b = blockIdx.x;            // 256 blocks: 64 i-chunks x 4 col-groups
  int chunk = b >> 2;
  int g = b & 3;
  int t = threadIdx.x;
  int j = (g << 10) + (t << 2);
  __shared__ float vals[64];
  int i0 = chunk << 6;
  if (t < 64) {
    // merge the 16 nump replicas inline
    float s = 0.f;
    #pragma unroll
    for (int r = 0; r < 16; ++r) s += ws[WS_NUMP + (r << 12) + i0 + t];
    // all 64 elements of this chunk share one head: h = chunk>>1
    float d = 0.f;
    int h = chunk >> 1;
    #pragma unroll
    for (int r = 0; r < 16; ++r) d += ws[WS_DENP + (r << 6) + h];
    vals[t] = s / d;
  }
  __syncthreads();
  float ax = 0.f, ay = 0.f, az = 0.f, aw = 0.f;
  #pragma unroll 4
  for (int r = 0; r < 64; ++r) {
    int i = i0 + r;
    float vi = vals[r];
    const fv4 w4 = ntload4(Wo + (size_t)i * E + j);
    ax += vi * w4.x; ay += vi * w4.y; az += vi * w4.z; aw += vi * w4.w;
  }
  if (chunk == 0) {
    const fv4 b4 = *reinterpret_cast<const fv4*>(bo + j);
    ax += b4.x; ay += b4.y; az += b4.z; aw += b4.w;
  }
  fv4 val = {ax, ay, az, aw};
  ntstore4(ws + WS_OPART + (chunk << 12) + j, val);
}

// ---------------- K5: final out_i = sum of 64 chunk partials -----------------
__global__ __launch_bounds__(256) void writeout(const float* __restrict__ ws,
                                                float* __restrict__ out) {
  int i = blockIdx.x * 256 + threadIdx.x;   // 16 blocks
  float s = 0.f;
  #pragma unroll 8
  for (int c = 0; c < 64; ++c) s += ws[WS_OPART + (c << 12) + i];
  out[i] = s;
}

extern "C" void kernel_launch(void* const* d_in, const int* in_sizes, int n_in,
                              void* d_out, int out_size, void* d_ws, size_t ws_size,
                              hipStream_t stream) {
  const float* x   = (const float*)d_in[0];
  const float* vin = (const float*)d_in[1];
  const float* kin = (const float*)d_in[2];
  const float* Wv  = (const float*)d_in[3];
  const float* bv  = (const float*)d_in[4];
  const float* Wq  = (const float*)d_in[5];
  const float* bq  = (const float*)d_in[6];
  const float* Wk  = (const float*)d_in[7];
  const float* bk  = (const float*)d_in[8];
  const float* Wo  = (const float*)d_in[9];
  const float* bo  = (const float*)d_in[10];
  float* out  = (float*)d_out;
  float* vout = out + E;
  float* kout = vout + (size_t)L * E;
  float* ws   = (float*)d_ws;

  zero_np<<<(WS_OPART - WS_NUMP + 255) / 256, 256, 0, stream>>>(ws);
  gemv_qkv<<<384, 256, 0, stream>>>(x, Wq, Wk, Wv, ws);
  qkvred<<<48, 256, 0, stream>>>(bq, bk, bv, ws);
  kvpass<<<L / SLOTS, 256, 0, stream>>>(kin, vin, kout, vout, ws);
  gemv_out<<<256, 256, 0, stream>>>(Wo, bo, ws);
  writeout<<<16, 256, 0, stream>>>(ws, out);
}